// Round 5
// baseline (137.516 us; speedup 1.0000x reference)
//
#include <hip/hip_runtime.h>
#include <hip/hip_bf16.h>

#define BB 64
#define TT 16
#define ROWS 1024
#define ADIM 32
#define HID 1536
#define NCAT 4
#define MT_MAX 20          // worst case sum ceil(cnt_c/4) = 19
#define NTILE 24           // HID/64
#define GRID_G (MT_MAX * NTILE)   // 480 = 8 * 60

typedef __attribute__((ext_vector_type(8))) short bf16x8;
typedef __attribute__((ext_vector_type(4))) float f32x4;

static __device__ __forceinline__ unsigned short f2bf(float f) {
    union { float f; unsigned int u; } v; v.f = f;
    unsigned int u = v.u + 0x7fff + ((v.u >> 16) & 1);   // RNE
    return (unsigned short)(u >> 16);
}
static __device__ __forceinline__ short f2bf_rne(float f) {
    __hip_bfloat16 h = __float2bfloat16(f);
    return __builtin_bit_cast(short, h);
}

// ---------------------------------------------------------------------------
// prep: group samples by category into padded 4-sample m-tiles.
// ---------------------------------------------------------------------------
__global__ void prep_kernel(const int* __restrict__ cat_ids,
                            int* __restrict__ msample, int* __restrict__ mcat) {
    __shared__ int counts[NCAT];
    const int t = threadIdx.x;
    if (t < NCAT) {
        int c = 0;
        for (int s = 0; s < BB; ++s) c += (cat_ids[s] == t);
        counts[t] = c;
    }
    __syncthreads();
    if (t < NCAT) {
        int off = 0;
        for (int c = 0; c < t; ++c) off += (counts[c] + 3) >> 2;
        const int mt = (counts[t] + 3) >> 2;
        int idx = 0;
        for (int s = 0; s < BB; ++s)
            if (cat_ids[s] == t) msample[off * 4 + (idx++)] = s;
        for (; idx < mt * 4; ++idx) msample[off * 4 + idx] = -1;
        for (int mm = 0; mm < mt; ++mm) mcat[off + mm] = t;
    }
    __syncthreads();
    if (t == 0) {
        int tot = 0;
        for (int c = 0; c < NCAT; ++c) tot += (counts[c] + 3) >> 2;
        for (int mm = tot; mm < MT_MAX; ++mm) mcat[mm] = -1;
    }
}

// ---------------------------------------------------------------------------
// build_x: X[row][0:1536] = actions @ W1[cat] + b1[cat]; X[row][1536:3072] = PE
// ---------------------------------------------------------------------------
__global__ void build_x_kernel(const float* __restrict__ actions,
                               const int* __restrict__ timesteps,
                               const int* __restrict__ cat_ids,
                               const float* __restrict__ W1,
                               const float* __restrict__ b1,
                               unsigned short* __restrict__ X) {
    const int s = blockIdx.x;
    const int part = blockIdx.y;
    const int t = threadIdx.x;
    if (part < 6) {
        const int cat = cat_ids[s];
        const int h = part * 256 + t;
        __shared__ float act[TT][ADIM];
        const float* ab = actions + (size_t)s * TT * ADIM;
        ((float*)act)[t]       = ab[t];
        ((float*)act)[t + 256] = ab[t + 256];
        __syncthreads();
        const float* W1c = W1 + (size_t)cat * ADIM * HID + h;
        float acc[TT];
        #pragma unroll
        for (int r = 0; r < TT; ++r) acc[r] = 0.f;
        #pragma unroll 8
        for (int d = 0; d < ADIM; ++d) {
            const float wv = W1c[(size_t)d * HID];
            #pragma unroll
            for (int r = 0; r < TT; ++r) acc[r] += act[r][d] * wv;
        }
        const float bias = b1[cat * HID + h];
        #pragma unroll
        for (int r = 0; r < TT; ++r)
            X[(size_t)(s * TT + r) * (2 * HID) + h] = f2bf(acc[r] + bias);
    } else {
        const float ts = (float)timesteps[s];
        #pragma unroll
        for (int j = 0; j < 6; ++j) {
            const int i = j * 256 + t;
            const int ii = (i < 768) ? i : i - 768;
            const float freq = expf(-9.210340371976184f * (float)ii * (1.0f / 768.0f));
            const float ang = ts * freq;
            const float v = (i < 768) ? sinf(ang) : cosf(ang);
            const unsigned short bv = f2bf(v);
            for (int r = 0; r < TT; ++r)
                X[(size_t)(s * TT + r) * (2 * HID) + HID + i] = bv;
        }
    }
}

// ---------------------------------------------------------------------------
// gemm_fused: single-wave 64x64 tile, FULL K (no split), fused bias(+swish),
//   3-stage register prefetch, no LDS, no barriers, XCD-swizzled grid.
// ---------------------------------------------------------------------------
template<int K, bool SWISH, bool BF16OUT>
__global__ __launch_bounds__(64, 1) void gemm_fused(
        const unsigned short* __restrict__ Xin,  // [ROWS][K] bf16
        const float* __restrict__ W,             // [NCAT][K][HID] fp32
        const float* __restrict__ bias,          // [NCAT][HID]
        const int* __restrict__ msample,
        const int* __restrict__ mcat,
        void* __restrict__ Out) {
    constexpr int NT = K / 32;
    static_assert(NT % 3 == 0, "NT must be divisible by 3");

    // bijective XCD swizzle: 480 = 8 xcds * 60 chunks, m-major order
    const int id  = blockIdx.x;
    const int g60 = (id & 7) * (GRID_G / 8) + (id >> 3);
    const int m   = g60 / NTILE;
    const int nt  = g60 - m * NTILE;
    const int cat = mcat[m];
    if (cat < 0) return;
    const int n0 = nt * 64;

    const int l   = threadIdx.x;
    const int col = l & 15;
    const int g   = l >> 4;

    int sidx[4];
    #pragma unroll
    for (int f = 0; f < 4; ++f) sidx[f] = msample[m * 4 + f];

    const unsigned short* aptr[4];
    #pragma unroll
    for (int f = 0; f < 4; ++f) {
        const int s = sidx[f] < 0 ? 0 : sidx[f];
        aptr[f] = Xin + ((size_t)s * TT + col) * K + g * 8;
    }
    const float* wptr = W + ((size_t)cat * K + g * 8) * HID + n0 + col;

    f32x4 acc[4][4];
    #pragma unroll
    for (int i = 0; i < 4; ++i)
        #pragma unroll
        for (int j = 0; j < 4; ++j) acc[i][j] = f32x4{0.f, 0.f, 0.f, 0.f};

    // 3-stage pipelines, all indices compile-time
    float  bs[3][32];
    bf16x8 as[3][4];

    auto issueB = [&](int t, int s) {
        if (t >= NT) return;                 // wave-uniform skip
        const float* wp = wptr + (size_t)t * 32 * HID;
        #pragma unroll
        for (int nf = 0; nf < 4; ++nf)
            #pragma unroll
            for (int j = 0; j < 8; ++j)
                bs[s][nf * 8 + j] = wp[(size_t)j * HID + nf * 16];
    };
    auto issueA = [&](int t, int s) {
        if (t >= NT) return;
        #pragma unroll
        for (int f = 0; f < 4; ++f)
            as[s][f] = *(const bf16x8*)(aptr[f] + t * 32);
    };
    auto step = [&](int s) {
        bf16x8 bfr[4];
        #pragma unroll
        for (int nf = 0; nf < 4; ++nf)
            #pragma unroll
            for (int j = 0; j < 8; ++j)
                bfr[nf][j] = f2bf_rne(bs[s][nf * 8 + j]);
        #pragma unroll
        for (int mf = 0; mf < 4; ++mf)
            #pragma unroll
            for (int nf = 0; nf < 4; ++nf)
                acc[mf][nf] = __builtin_amdgcn_mfma_f32_16x16x32_bf16(
                    as[s][mf], bfr[nf], acc[mf][nf], 0, 0, 0);
    };

    issueB(0, 0); issueA(0, 0);
    issueB(1, 1); issueA(1, 1);
    for (int tt = 0; tt < NT; tt += 3) {
        issueB(tt + 2, 2); issueA(tt + 2, 2);
        step(0);
        issueB(tt + 3, 0); issueA(tt + 3, 0);
        step(1);
        issueB(tt + 4, 1); issueA(tt + 4, 1);
        step(2);
    }

    // fused epilogue: bias (+swish), direct store. D row = g*4+r, col = l&15.
    const float* bc = bias + (size_t)cat * HID + n0 + col;
    #pragma unroll
    for (int mf = 0; mf < 4; ++mf) {
        if (sidx[mf] < 0) continue;
        const size_t rowbase = (size_t)sidx[mf] * TT + g * 4;
        #pragma unroll
        for (int nf = 0; nf < 4; ++nf) {
            const float bv = bc[nf * 16];
            #pragma unroll
            for (int r = 0; r < 4; ++r) {
                float v = acc[mf][nf][r] + bv;
                if (SWISH) v = v / (1.f + __expf(-v));
                const size_t off = (rowbase + r) * HID + n0 + nf * 16 + col;
                if (BF16OUT) ((unsigned short*)Out)[off] = f2bf(v);
                else         ((float*)Out)[off] = v;
            }
        }
    }
}

// ---------------------------------------------------------------------------
extern "C" void kernel_launch(void* const* d_in, const int* in_sizes, int n_in,
                              void* d_out, int out_size, void* d_ws, size_t ws_size,
                              hipStream_t stream) {
    const float* actions   = (const float*)d_in[0];
    const int*   timesteps = (const int*)d_in[1];
    const int*   cat_ids   = (const int*)d_in[2];
    const float* W1        = (const float*)d_in[3];
    const float* b1        = (const float*)d_in[4];
    const float* W2        = (const float*)d_in[5];
    const float* b2        = (const float*)d_in[6];
    const float* W3        = (const float*)d_in[7];
    const float* b3        = (const float*)d_in[8];

    char* ws = (char*)d_ws;
    unsigned short* X = (unsigned short*)ws;                 // 6,291,456 B
    unsigned short* H = (unsigned short*)(ws + 6291456);     // 3,145,728 B
    int* msample      = (int*)(ws + 9437184);
    int* mcat         = msample + MT_MAX * 4;

    prep_kernel<<<1, 64, 0, stream>>>(cat_ids, msample, mcat);
    build_x_kernel<<<dim3(BB, 7), 256, 0, stream>>>(actions, timesteps, cat_ids, W1, b1, X);

    gemm_fused<2 * HID, true, true><<<GRID_G, 64, 0, stream>>>(
        X, W2, b2, msample, mcat, H);
    gemm_fused<HID, false, false><<<GRID_G, 64, 0, stream>>>(
        H, W3, b3, msample, mcat, d_out);
}